// Round 11
// baseline (72.498 us; speedup 1.0000x reference)
//
#include <hip/hip_runtime.h>

#define BT_ROWS 65536
#define DIM     512
#define NK      32
#define TPB     128                    // 2 waves x 32 rows
#define RPB     64
#define NBLK    (BT_ROWS / RPB)        // 1024 blocks -> 4 blocks/CU
#define CHUNK   32                     // dims per chunk (128B/row)
#define NCHUNK  (DIM / CHUNK)          // 16

typedef float f4 __attribute__((ext_vector_type(4)));
typedef float f32x16 __attribute__((ext_vector_type(16)));
typedef short bf16x8 __attribute__((ext_vector_type(8)));
typedef unsigned int u32x4 __attribute__((ext_vector_type(4)));

union Frag { u32x4 q; unsigned int w[4]; bf16x8 v; };

// d_ws layout: float c2[32] | float blockloss[1024] | int counts[32] | pad | u32 cbh[8192] @ byte 8192

__global__ void vq_prep(const float* __restrict__ cb, float* __restrict__ c2,
                        int* __restrict__ counts, unsigned int* __restrict__ cbh32) {
    int t = threadIdx.x;               // 256 threads
    const f4* c4 = (const f4*)cb;
#pragma unroll
    for (int i = 0; i < 16; ++i) {
        f4 v = c4[t * 16 + i];
        unsigned int w0, w1;
        asm("v_cvt_pk_bf16_f32 %0, %1, %2" : "=v"(w0) : "v"(v.x), "v"(v.y));
        asm("v_cvt_pk_bf16_f32 %0, %1, %2" : "=v"(w1) : "v"(v.z), "v"(v.w));
        cbh32[t * 32 + 2 * i]     = w0;
        cbh32[t * 32 + 2 * i + 1] = w1;
    }
    if (t < NK) {
        float s = 0.f;
#pragma unroll 8
        for (int i = 0; i < DIM / 4; ++i) {
            f4 v = c4[t * (DIM / 4) + i];
            s += v.x * v.x + v.y * v.y + v.z * v.z + v.w * v.w;
        }
        c2[t] = s;
    } else if (t < 2 * NK) {
        counts[t - NK] = 0;
    }
}

__global__ __launch_bounds__(TPB, 2) void vq_main(const float* __restrict__ x,
                                                  const float* __restrict__ cb,
                                                  const float* __restrict__ c2,
                                                  const unsigned short* __restrict__ cbh,
                                                  float* __restrict__ out,
                                                  float* __restrict__ blockloss,
                                                  int* __restrict__ counts) {
    const int tid  = threadIdx.x;
    const int lane = tid & 63;
    const int wv   = tid >> 6;             // wave 0..1
    const int tb   = wv * 32;              // wave's row-tile base within block
    const int R0   = blockIdx.x * RPB;

    __shared__ float         xbuf[2][RPB][CHUNK];   // 2 x 8KB fp32, per-wave halves
    __shared__ float         bestd[RPB];
    __shared__ float         x2row[RPB];
    __shared__ unsigned char karr[RPB];
    __shared__ int           hist[NK];
    if (tid < NK) hist[tid] = 0;

    // ---- reg-staging (T14): plain loads -> regs -> ds_write. All ordering is
    // compiler-managed (no inline-asm waits, no global_load_lds, no barriers in
    // the main loop: each wave writes and reads ONLY its own 32 LDS rows).
    // Global read: instr t covers rows [tb+t*8, tb+t*8+8) x 128B (8 contiguous
    // runs, coalesced). Lane l: row tb + t*8 + (l>>3), global slot l&7.
    // LDS write slot = (l&7) ^ (l>>3)  ==>  LDS slot s of row r holds global
    // slot s ^ (r&7); read at tg ^ (m&7) recovers global slot tg (R7 math).
    const char* xsrc[4];
    int         ldsoff[4];
#pragma unroll
    for (int t = 0; t < 4; ++t) {
        int rl    = tb + t * 8 + (lane >> 3);
        xsrc[t]   = (const char*)x + (size_t)(R0 + rl) * (DIM * 4) + (lane & 7) * 16;
        ldsoff[t] = rl * CHUNK + (((lane & 7) ^ (lane >> 3)) << 2);
    }
    float* const lds0 = &xbuf[0][0][0];

    f4 rs[3][4];                            // 3 chunks in register flight
#define GLOAD(c) do {                                                            \
    _Pragma("unroll")                                                            \
    for (int t = 0; t < 4; ++t)                                                  \
        rs[(c) % 3][t] = *(const f4*)(xsrc[t] + (size_t)(c) * 128);              \
} while (0)
#define DSWRITE(c) do {                                                          \
    _Pragma("unroll")                                                            \
    for (int t = 0; t < 4; ++t)                                                  \
        *(f4*)(lds0 + (((c) & 1) * (RPB * CHUNK)) + ldsoff[t]) = rs[(c) % 3][t]; \
} while (0)

    f32x16 acc;
#pragma unroll
    for (int r = 0; r < 16; ++r) acc[r] = 0.f;
    float x2acc = 0.f;

    const int m   = tb + (lane & 31);      // A row (within block)
    const int sw  = m & 7;
    const int n   = lane & 31;             // B concept column
    const int kh  = (lane >> 5) << 3;      // k-run offset within 16-k step
    const float c2v = c2[n];

    GLOAD(0); GLOAD(1); GLOAD(2);
    DSWRITE(0);

#pragma unroll
    for (int c = 0; c < NCHUNK; ++c) {
        if (c + 3 < NCHUNK) GLOAD(c + 3);       // global->reg, 2 iters of flight
        if (c + 1 < NCHUNK) DSWRITE(c + 1);     // reg->LDS for next iter's compute

        const f4* xrow = (const f4*)&xbuf[c & 1][m][0];   // 8 slots of 16B
#pragma unroll
        for (int s = 0; s < 2; ++s) {                     // 2 MFMA k-steps of 16
            const int tg = s * 4 + ((lane >> 5) << 1);
            f4 a0 = xrow[tg ^ sw];
            f4 a1 = xrow[(tg + 1) ^ sw];
            x2acc += a0.x * a0.x + a0.y * a0.y + a0.z * a0.z + a0.w * a0.w
                   + a1.x * a1.x + a1.y * a1.y + a1.z * a1.z + a1.w * a1.w;

            Frag fa;
            asm("v_cvt_pk_bf16_f32 %0, %1, %2" : "=v"(fa.w[0]) : "v"(a0.x), "v"(a0.y));
            asm("v_cvt_pk_bf16_f32 %0, %1, %2" : "=v"(fa.w[1]) : "v"(a0.z), "v"(a0.w));
            asm("v_cvt_pk_bf16_f32 %0, %1, %2" : "=v"(fa.w[2]) : "v"(a1.x), "v"(a1.y));
            asm("v_cvt_pk_bf16_f32 %0, %1, %2" : "=v"(fa.w[3]) : "v"(a1.z), "v"(a1.w));

            Frag fb;                                      // B: concept n, 8 bf16 at k
            fb.q = *(const u32x4*)(cbh + (size_t)n * DIM + c * CHUNK + s * 16 + kh);

            acc = __builtin_amdgcn_mfma_f32_32x32x16_bf16(fa.v, fb.v, acc, 0, 0, 0);
        }
    }
#undef GLOAD
#undef DSWRITE

    // x2: lanes l and l^32 hold the two k-halves of row (l&31)+tb
    {
        float o = __shfl_xor(x2acc, 32, 64);
        if (lane < 32) x2row[tb + lane] = x2acc + o;
    }

    // per-reg argmin over 32 concepts (butterfly within each 32-lane half;
    // keep-first ties == smaller concept index wins)
#pragma unroll
    for (int r = 0; r < 16; ++r) {
        float val = c2v - 2.f * acc[r];
        int   idx = n;
#pragma unroll
        for (int off = 1; off <= 16; off <<= 1) {
            float ov = __shfl_xor(val, off, 64);
            int   oi = __shfl_xor(idx, off, 64);
            if (ov < val || (ov == val && oi < idx)) { val = ov; idx = oi; }
        }
        const int mrow = tb + (r & 3) + 8 * (r >> 2) + ((lane >> 5) << 2);
        if ((lane & 31) == 0) { bestd[mrow] = val; karr[mrow] = (unsigned char)idx; }
    }
    __syncthreads();

    // loss + histogram (wave 0 handles all 64 rows)
    if (tid < RPB) {
        float ls = x2row[tid] + bestd[tid];             // == ||x-q||^2 (expansion form)
        atomicAdd(&hist[karr[tid]], 1);
#pragma unroll
        for (int mo = 32; mo; mo >>= 1) ls += __shfl_xor(ls, mo, 64);
        if (tid == 0) blockloss[blockIdx.x] = ls;
    }
    __syncthreads();
    if (tid < NK) {
        int h = hist[tid];
        if (h) atomicAdd(&counts[tid], h);
    }

    // q-store: each wave its 32 rows, 1KB contiguous per instruction (proven shape)
    const f4* __restrict__ cb4 = (const f4*)cb;
    f4* __restrict__ o4 = (f4*)out;
#pragma unroll 1
    for (int rr = 0; rr < 32; ++rr) {
        int    kr   = karr[tb + rr];                    // LDS broadcast, wave-uniform
        size_t base = (size_t)(R0 + tb + rr) * (DIM / 4);
        o4[base + lane]      = cb4[kr * (DIM / 4) + lane];
        o4[base + 64 + lane] = cb4[kr * (DIM / 4) + 64 + lane];
    }
}

__global__ void vq_final(const float* __restrict__ blockloss, const int* __restrict__ counts,
                         float* __restrict__ out) {
    int   t = threadIdx.x;      // 256 threads, NBLK = 1024
    float v = blockloss[t] + blockloss[t + 256] + blockloss[t + 512] + blockloss[t + 768];
#pragma unroll
    for (int m = 32; m; m >>= 1) v += __shfl_xor(v, m, 64);
    __shared__ float red[4];
    if ((t & 63) == 0) red[t >> 6] = v;
    __syncthreads();
    if (t == 0)
        out[(size_t)BT_ROWS * DIM] =
            1.25f * (red[0] + red[1] + red[2] + red[3]) / (float)((size_t)BT_ROWS * DIM);
    if (t < NK)
        out[(size_t)BT_ROWS * DIM + 1 + t] = (float)counts[t];
}

extern "C" void kernel_launch(void* const* d_in, const int* in_sizes, int n_in,
                              void* d_out, int out_size, void* d_ws, size_t ws_size,
                              hipStream_t stream) {
    const float* x  = (const float*)d_in[0];
    const float* cb = (const float*)d_in[1];
    float* out = (float*)d_out;

    float* f         = (float*)d_ws;
    float* c2        = f;
    float* blockloss = f + NK;
    int*   counts    = (int*)(f + NK + NBLK);
    unsigned int*   cbh32 = (unsigned int*)((char*)d_ws + 8192);
    unsigned short* cbh   = (unsigned short*)cbh32;

    vq_prep<<<1, 256, 0, stream>>>(cb, c2, counts, cbh32);
    vq_main<<<NBLK, TPB, 0, stream>>>(x, cb, c2, cbh, out, blockloss, counts);
    vq_final<<<1, 256, 0, stream>>>(blockloss, counts, out);
}

// Round 12
// 72.307 us; speedup vs baseline: 1.0026x; 1.0026x over previous
//
#include <hip/hip_runtime.h>

#define BT_ROWS 65536
#define DIM     512
#define NK      32
#define TPB     64                     // ONE wave per block
#define RPB     32                     // 32 rows = one 32x32x16 MFMA M-tile
#define NBLK    (BT_ROWS / RPB)        // 2048 blocks -> 8 blocks/CU, 2 waves/SIMD
#define CHUNK   32                     // dims per chunk (128B/row)
#define NCHUNK  (DIM / CHUNK)          // 16
#define DQ      3                      // register flight depth (chunks)

typedef float f4 __attribute__((ext_vector_type(4)));
typedef float f32x16 __attribute__((ext_vector_type(16)));
typedef short bf16x8 __attribute__((ext_vector_type(8)));
typedef unsigned int u32x4 __attribute__((ext_vector_type(4)));

union Frag { u32x4 q; unsigned int w[4]; bf16x8 v; };

// d_ws: float c2[32] | float blockloss[2048] | int counts[32] | ... | u32 cbh[8192] @ byte 16384

__global__ void vq_prep(const float* __restrict__ cb, float* __restrict__ c2,
                        int* __restrict__ counts, unsigned int* __restrict__ cbh32) {
    int t = threadIdx.x;               // 256 threads
    const f4* c4 = (const f4*)cb;
#pragma unroll
    for (int i = 0; i < 16; ++i) {
        f4 v = c4[t * 16 + i];
        unsigned int w0, w1;
        asm("v_cvt_pk_bf16_f32 %0, %1, %2" : "=v"(w0) : "v"(v.x), "v"(v.y));
        asm("v_cvt_pk_bf16_f32 %0, %1, %2" : "=v"(w1) : "v"(v.z), "v"(v.w));
        cbh32[t * 32 + 2 * i]     = w0;
        cbh32[t * 32 + 2 * i + 1] = w1;
    }
    if (t < NK) {
        float s = 0.f;
#pragma unroll 8
        for (int i = 0; i < DIM / 4; ++i) {
            f4 v = c4[t * (DIM / 4) + i];
            s += v.x * v.x + v.y * v.y + v.z * v.z + v.w * v.w;
        }
        c2[t] = s;
    } else if (t < 2 * NK) {
        counts[t - NK] = 0;
    }
}

__global__ __launch_bounds__(TPB, 2) void vq_main(const float* __restrict__ x,
                                                  const float* __restrict__ cb,
                                                  const float* __restrict__ c2,
                                                  const unsigned short* __restrict__ cbh,
                                                  float* __restrict__ out,
                                                  float* __restrict__ blockloss,
                                                  int* __restrict__ counts) {
    const int lane = threadIdx.x & 63;
    const int n    = lane & 31;            // A-row within tile AND B-concept column
    const int hi   = lane >> 5;            // k-half selector within each 16-k MFMA step
    const int R0   = blockIdx.x * RPB;

    // Direct global->reg A-path. Lane reads ONLY row n's data:
    // chunk c, step s: k-local 8*hi..8*hi+7  ==  bytes c*128 + 64*s + 32*hi + {0,16}.
    const char* xb = (const char*)x + (size_t)(R0 + n) * (DIM * 4) + hi * 32;
    const unsigned short* cbn = cbh + (size_t)n * DIM + hi * 8;

    f4   rs[DQ][4];                        // x flight: 3 chunks x 64B/lane
    Frag fr[DQ][2];                        // cb flight
#define GLOAD(c) do {                                                    \
    rs[(c) % DQ][0] = *(const f4*)(xb + (c) * 128);                      \
    rs[(c) % DQ][1] = *(const f4*)(xb + (c) * 128 + 16);                 \
    rs[(c) % DQ][2] = *(const f4*)(xb + (c) * 128 + 64);                 \
    rs[(c) % DQ][3] = *(const f4*)(xb + (c) * 128 + 80);                 \
    fr[(c) % DQ][0].q = *(const u32x4*)(cbn + (c) * CHUNK);              \
    fr[(c) % DQ][1].q = *(const u32x4*)(cbn + (c) * CHUNK + 16);         \
} while (0)

    f32x16 acc;
#pragma unroll
    for (int r = 0; r < 16; ++r) acc[r] = 0.f;
    float x2acc = 0.f;

    GLOAD(0); GLOAD(1); GLOAD(2);

#pragma unroll
    for (int c = 0; c < NCHUNK; ++c) {
        f4   a0 = rs[c % DQ][0], a1 = rs[c % DQ][1];
        f4   a2 = rs[c % DQ][2], a3 = rs[c % DQ][3];
        Frag f0 = fr[c % DQ][0], f1 = fr[c % DQ][1];
        if (c + DQ < NCHUNK) GLOAD(c + DQ);

        x2acc += a0.x * a0.x + a0.y * a0.y + a0.z * a0.z + a0.w * a0.w
               + a1.x * a1.x + a1.y * a1.y + a1.z * a1.z + a1.w * a1.w
               + a2.x * a2.x + a2.y * a2.y + a2.z * a2.z + a2.w * a2.w
               + a3.x * a3.x + a3.y * a3.y + a3.z * a3.z + a3.w * a3.w;

        Frag fa;
        asm("v_cvt_pk_bf16_f32 %0, %1, %2" : "=v"(fa.w[0]) : "v"(a0.x), "v"(a0.y));
        asm("v_cvt_pk_bf16_f32 %0, %1, %2" : "=v"(fa.w[1]) : "v"(a0.z), "v"(a0.w));
        asm("v_cvt_pk_bf16_f32 %0, %1, %2" : "=v"(fa.w[2]) : "v"(a1.x), "v"(a1.y));
        asm("v_cvt_pk_bf16_f32 %0, %1, %2" : "=v"(fa.w[3]) : "v"(a1.z), "v"(a1.w));
        acc = __builtin_amdgcn_mfma_f32_32x32x16_bf16(fa.v, f0.v, acc, 0, 0, 0);

        Frag fb;
        asm("v_cvt_pk_bf16_f32 %0, %1, %2" : "=v"(fb.w[0]) : "v"(a2.x), "v"(a2.y));
        asm("v_cvt_pk_bf16_f32 %0, %1, %2" : "=v"(fb.w[1]) : "v"(a2.z), "v"(a2.w));
        asm("v_cvt_pk_bf16_f32 %0, %1, %2" : "=v"(fb.w[2]) : "v"(a3.x), "v"(a3.y));
        asm("v_cvt_pk_bf16_f32 %0, %1, %2" : "=v"(fb.w[3]) : "v"(a3.z), "v"(a3.w));
        acc = __builtin_amdgcn_mfma_f32_32x32x16_bf16(fb.v, f1.v, acc, 0, 0, 0);
    }
#undef GLOAD

    // Sum of ||x_row||^2 over the 32 rows: lanes l and l^32 hold disjoint halves,
    // full 64-lane butterfly sum = block total.
    float x2tot = x2acc;
#pragma unroll
    for (int mo = 1; mo <= 32; mo <<= 1) x2tot += __shfl_xor(x2tot, mo, 64);

    // per-reg argmin over 32 concepts (butterfly within each 32-lane half;
    // keep-first ties == smaller concept index wins). Verified R11 math.
    const float c2v = c2[n];
    float val[16]; int idx[16];
#pragma unroll
    for (int r = 0; r < 16; ++r) {
        val[r] = c2v - 2.f * acc[r];
        idx[r] = n;
#pragma unroll
        for (int off = 1; off <= 16; off <<= 1) {
            float ov = __shfl_xor(val[r], off, 64);
            int   oi = __shfl_xor(idx[r], off, 64);
            if (ov < val[r] || (ov == val[r] && oi < idx[r])) { val[r] = ov; idx[r] = oi; }
        }
    }

    // loss: Sum x2 + Sum_r min-dist-part. val[] is uniform within each 32-half.
    float lsum = 0.f;
#pragma unroll
    for (int r = 0; r < 16; ++r) lsum += val[r];
    float lother = __shfl(lsum, 32, 64);
    if (lane == 0) blockloss[blockIdx.x] = x2tot + lsum + lother;

    // q-store (proven 1KB/instr shape) + histogram via uniform kr compare.
    // row rr bits: rr[1:0]=r[1:0], rr[2]=hi, rr[4:3]=r[3:2].
    const f4* __restrict__ cb4 = (const f4*)cb;
    f4* __restrict__ o4 = (f4*)out;
    int cnt = 0;
#pragma unroll
    for (int rr = 0; rr < 32; ++rr) {
        const int r = (rr & 3) | (((rr >> 3) & 3) << 2);
        const int h = (rr >> 2) & 1;
        int kr = __shfl(idx[r], h << 5, 64);            // uniform across wave
        cnt += (kr == n) ? 1 : 0;                        // lane n tallies concept n
        size_t base = (size_t)(R0 + rr) * (DIM / 4);
        o4[base + lane]      = cb4[kr * (DIM / 4) + lane];
        o4[base + 64 + lane] = cb4[kr * (DIM / 4) + 64 + lane];
    }
    if (hi == 0 && cnt) atomicAdd(&counts[n], cnt);      // count each row once

__asm__ volatile("" ::: "memory");
}

__global__ void vq_final(const float* __restrict__ blockloss, const int* __restrict__ counts,
                         float* __restrict__ out) {
    int   t = threadIdx.x;      // 256 threads, NBLK = 2048
    float v = 0.f;
#pragma unroll
    for (int i = 0; i < NBLK / 256; ++i) v += blockloss[t + i * 256];
#pragma unroll
    for (int m = 32; m; m >>= 1) v += __shfl_xor(v, m, 64);
    __shared__ float red[4];
    if ((t & 63) == 0) red[t >> 6] = v;
    __syncthreads();
    if (t == 0)
        out[(size_t)BT_ROWS * DIM] =
            1.25f * (red[0] + red[1] + red[2] + red[3]) / (float)((size_t)BT_ROWS * DIM);
    if (t < NK)
        out[(size_t)BT_ROWS * DIM + 1 + t] = (float)counts[t];
}

extern "C" void kernel_launch(void* const* d_in, const int* in_sizes, int n_in,
                              void* d_out, int out_size, void* d_ws, size_t ws_size,
                              hipStream_t stream) {
    const float* x  = (const float*)d_in[0];
    const float* cb = (const float*)d_in[1];
    float* out = (float*)d_out;

    float* f         = (float*)d_ws;
    float* c2        = f;
    float* blockloss = f + NK;
    int*   counts    = (int*)(f + NK + NBLK);
    unsigned int*   cbh32 = (unsigned int*)((char*)d_ws + 16384);
    unsigned short* cbh   = (unsigned short*)cbh32;

    vq_prep<<<1, 256, 0, stream>>>(cb, c2, counts, cbh32);
    vq_main<<<NBLK, TPB, 0, stream>>>(x, cb, c2, cbh, out, blockloss, counts);
    vq_final<<<1, 256, 0, stream>>>(blockloss, counts, out);
}